// Round 1
// baseline (2600.202 us; speedup 1.0000x reference)
//
#include <hip/hip_runtime.h>
#include <hip/hip_bf16.h>
#include <math.h>

#define SEQ    1024
#define EMB    512
#define HID    512
#define G4     2048   // 4*HID
#define NBLK   32     // blocks per redundancy group
#define NGRP   8      // redundancy groups (one per XCD under round-robin dispatch)
#define UPB    16     // hidden units per block
#define NSLOT  4      // rotating h slots (WAR-safe at distance 4)

typedef unsigned long long u64;

// ---------------------------------------------------------------------------
// Phase A: x_gates[t][r] = dot(emb[tok[t]], w_ih[r]) + b_ih[r] + b_hh[r]
// 64x64 tile, K-chunks of 64, 4x4 micro-tile per thread.  (UNCHANGED —
// arithmetic order must stay bit-identical.)
// ---------------------------------------------------------------------------
__global__ __launch_bounds__(256) void xgates_kernel(
    const int* __restrict__ tok, const float* __restrict__ emb,
    const float* __restrict__ w_ih, const float* __restrict__ b_ih,
    const float* __restrict__ b_hh, float* __restrict__ xg)
{
  __shared__ float xs[64][68];   // +4 pad breaks power-of-2 bank stride
  __shared__ float wsh[64][68];
  __shared__ int   tok_s[64];

  const int tid = threadIdx.x;
  const int r0  = (int)blockIdx.x * 64;   // gate-row tile
  const int t0  = (int)blockIdx.y * 64;   // seq tile

  if (tid < 64) tok_s[tid] = tok[t0 + tid];
  __syncthreads();

  const int tx = tid & 15;   // r micro
  const int ty = tid >> 4;   // t micro

  float acc[4][4];
#pragma unroll
  for (int i = 0; i < 4; ++i)
#pragma unroll
    for (int j = 0; j < 4; ++j) acc[i][j] = 0.f;

  for (int kc = 0; kc < EMB; kc += 64) {
#pragma unroll
    for (int it = 0; it < 4; ++it) {
      int id  = it * 256 + tid;    // 0..1023 float4 slots
      int row = id >> 4;           // 0..63
      int c4  = id & 15;           // 0..15
      float4 xv = *(const float4*)(emb + (size_t)tok_s[row] * EMB + kc + c4 * 4);
      *(float4*)&xs[row][c4 * 4] = xv;
      float4 wv = *(const float4*)(w_ih + (size_t)(r0 + row) * EMB + kc + c4 * 4);
      *(float4*)&wsh[row][c4 * 4] = wv;
    }
    __syncthreads();

#pragma unroll
    for (int k4 = 0; k4 < 16; ++k4) {
      float4 xv[4], wv[4];
#pragma unroll
      for (int i = 0; i < 4; ++i) xv[i] = *(const float4*)&xs[ty * 4 + i][k4 * 4];
#pragma unroll
      for (int j = 0; j < 4; ++j) wv[j] = *(const float4*)&wsh[tx * 4 + j][k4 * 4];
#pragma unroll
      for (int i = 0; i < 4; ++i)
#pragma unroll
        for (int j = 0; j < 4; ++j) {
          acc[i][j] += xv[i].x * wv[j].x + xv[i].y * wv[j].y
                     + xv[i].z * wv[j].z + xv[i].w * wv[j].w;
        }
    }
    __syncthreads();
  }

  const int rbase = r0 + tx * 4;
  float bias[4];
#pragma unroll
  for (int j = 0; j < 4; ++j) bias[j] = b_ih[rbase + j] + b_hh[rbase + j];

#pragma unroll
  for (int i = 0; i < 4; ++i) {
    int t = t0 + ty * 4 + i;
    float4 o;
    o.x = acc[i][0] + bias[0];
    o.y = acc[i][1] + bias[1];
    o.z = acc[i][2] + bias[2];
    o.w = acc[i][3] + bias[3];
    *(float4*)(xg + (size_t)t * G4 + rbase) = o;
  }
}

// ---------------------------------------------------------------------------
// Phase B: sequential LSTM scan.
//
// NEW STRUCTURE: 8 redundant groups x 32 blocks (grid=256, one block per CU).
// group gid = blockIdx.x % 8  -> under round-robin dispatch all 32 blocks of
// a group share one XCD.  Each group independently computes ALL 512 h units
// with arithmetic bit-identical to the old 32-block ensemble, so every group
// produces identical h bits.
//
// h exchange is intra-group through a group-private buffer:
//   producer: plain global_store_dwordx2  -> lands in the XCD's L2 (~150cy)
//   consumer: sc0 (L1-bypass) load        -> served by the same L2 (~250cy)
// instead of agent-scope atomics that round-trip the chip-wide L3/IF
// (~2400cy/step observed).  The (tag<<32)|f32 word makes stale reads benign,
// and producers ALSO store agent-scope to the old hslot buffer; consumers
// escalate to an agent-scope load every 8 failed fast polls.  So if dispatch
// is not round-robin or sc0 semantics differ, the kernel degrades to the old
// (correct) protocol instead of hanging.
// ---------------------------------------------------------------------------
__global__ __launch_bounds__(512) void lstm_scan_kernel(
    const float* __restrict__ xg, const float* __restrict__ w_hh,
    u64* hslot /* agent: [NSLOT][HID] */,
    u64* hfast /* L2-local: [NGRP][NSLOT][HID] */)
{
  __shared__ float h_lds[512];          // per-wave disjoint 64-float regions
  __shared__ float part_lds[2][8 * 64]; // double-buffered partials

  const int tid  = threadIdx.x;
  const int gid  = (int)blockIdx.x & (NGRP - 1);  // redundancy group (~XCD)
  const int ublk = (int)blockIdx.x >> 3;          // unit-block 0..31
  const int w    = tid >> 6;            // wave id = k-segment
  const int l    = tid & 63;            // lane   = local gate row
  const int q    = l >> 4;              // gate type (i,f,g,o)
  const int jj   = l & 15;              // local hidden unit
  const int grow = q * HID + ublk * UPB + jj;  // global gate row

  u64* fbase = hfast + (size_t)gid * NSLOT * HID;

  // This thread's 64 w_hh weights -> VGPRs.
  float wreg[64];
  {
    const float* wp = w_hh + (size_t)grow * HID + w * 64;
#pragma unroll
    for (int k4 = 0; k4 < 16; ++k4) {
      float4 v = ((const float4*)wp)[k4];
      wreg[4 * k4 + 0] = v.x; wreg[4 * k4 + 1] = v.y;
      wreg[4 * k4 + 2] = v.z; wreg[4 * k4 + 3] = v.w;
    }
  }

  float c_reg = 0.f;                       // cell state (wave0 lanes 0..15)
  float xgv = (w == 0) ? xg[grow] : 0.f;   // x_gates[0][grow]

  for (int t = 0; t < SEQ; ++t) {
    // --- h arrival: fast L2-local poll with agent-scope escalation --------
    const u64* fsrc = fbase + (size_t)(t & (NSLOT - 1)) * HID + tid;
    const u64* ssrc = hslot + (size_t)(t & (NSLOT - 1)) * HID + tid;
    u64 word;
    int spins = 0;
    while (true) {
      // sc0 = L1 bypass; served by this XCD's L2 where same-XCD plain
      // stores land.  Stale tag -> retry (never wrong data: 8B words are
      // single-copy atomic, tag+payload travel together).
      asm volatile("global_load_dwordx2 %0, %1, off sc0\n\t"
                   "s_waitcnt vmcnt(0)"
                   : "=v"(word) : "v"(fsrc) : "memory");
      if ((unsigned)(word >> 32) == (unsigned)t) break;
      if (((++spins) & 7) == 0) {
        // fallback: the proven agent-scope path (L3 coherence point)
        word = __hip_atomic_load(ssrc, __ATOMIC_RELAXED, __HIP_MEMORY_SCOPE_AGENT);
        if ((unsigned)(word >> 32) == (unsigned)t) break;
      }
    }
    h_lds[tid] = __uint_as_float((unsigned)(word & 0xffffffffu));
    // No barrier: wave w reads only h_lds[64w..64w+63], written by its own
    // lanes (lockstep within a wave; lgkmcnt orders the ds ops).

    const float*  hb  = &h_lds[w * 64];
    const float4* hb4 = (const float4*)hb;
    float p0 = 0.f, p1 = 0.f, p2 = 0.f, p3 = 0.f;
    // float4 LDS reads; per-accumulator add order identical to the scalar
    // version (ascending k within each p) -> bit-identical result.
#pragma unroll
    for (int k4 = 0; k4 < 4; ++k4) {
      float4 h0 = hb4[k4];
      float4 h1 = hb4[k4 + 4];
      float4 h2 = hb4[k4 + 8];
      float4 h3 = hb4[k4 + 12];
      p0 += wreg[4 * k4 + 0] * h0.x; p0 += wreg[4 * k4 + 1] * h0.y;
      p0 += wreg[4 * k4 + 2] * h0.z; p0 += wreg[4 * k4 + 3] * h0.w;
      p1 += wreg[16 + 4 * k4 + 0] * h1.x; p1 += wreg[16 + 4 * k4 + 1] * h1.y;
      p1 += wreg[16 + 4 * k4 + 2] * h1.z; p1 += wreg[16 + 4 * k4 + 3] * h1.w;
      p2 += wreg[32 + 4 * k4 + 0] * h2.x; p2 += wreg[32 + 4 * k4 + 1] * h2.y;
      p2 += wreg[32 + 4 * k4 + 2] * h2.z; p2 += wreg[32 + 4 * k4 + 3] * h2.w;
      p3 += wreg[48 + 4 * k4 + 0] * h3.x; p3 += wreg[48 + 4 * k4 + 1] * h3.y;
      p3 += wreg[48 + 4 * k4 + 2] * h3.z; p3 += wreg[48 + 4 * k4 + 3] * h3.w;
    }
    part_lds[t & 1][w * 64 + l] = (p0 + p1) + (p2 + p3);
    __syncthreads();   // the only barrier per step

    if (w == 0) {
      const float* pp = &part_lds[t & 1][0];
      float s = ((pp[l]       + pp[64 + l]) + (pp[128 + l] + pp[192 + l]))
              + ((pp[256 + l] + pp[320 + l]) + (pp[384 + l] + pp[448 + l]));
      float gv = s + xgv;

      // prefetch next step's xg (used next iteration -> latency hidden)
      int tn = (t + 1 < SEQ) ? (t + 1) : (SEQ - 1);
      xgv = xg[(size_t)tn * G4 + grow];

      // gather the 4 gate values for unit jj into lanes 0..15
      float gi = __shfl(gv, jj,      64);
      float gf = __shfl(gv, jj + 16, 64);
      float gg = __shfl(gv, jj + 32, 64);
      float go = __shfl(gv, jj + 48, 64);

      if (l < UPB) {
        const float LOG2E = 1.442695041f;
        float i_ = 1.f / (1.f + __builtin_exp2f(-LOG2E * gi));
        float f_ = 1.f / (1.f + __builtin_exp2f(-LOG2E * gf));
        float g_ = 2.f / (1.f + __builtin_exp2f(-2.f * LOG2E * gg)) - 1.f;
        float o_ = 1.f / (1.f + __builtin_exp2f(-LOG2E * go));
        c_reg = f_ * c_reg + i_ * g_;
        float hv = o_ * (2.f / (1.f + __builtin_exp2f(-2.f * LOG2E * c_reg)) - 1.f);
        u64 outw = ((u64)(unsigned)(t + 1) << 32) | (u64)__float_as_uint(hv);

        // FAST path first (critical): plain store -> local XCD L2.
        u64* fdst = fbase + (size_t)((t + 1) & (NSLOT - 1)) * HID + ublk * UPB + jj;
        asm volatile("global_store_dwordx2 %0, %1, off"
                     :: "v"(fdst), "v"(outw) : "memory");
        // Fallback + final-output path: agent scope (chip-visible).
        __hip_atomic_store(hslot + (size_t)((t + 1) & (NSLOT - 1)) * HID + ublk * UPB + jj,
                           outw, __ATOMIC_RELAXED, __HIP_MEMORY_SCOPE_AGENT);
      }
    }
  }
}

// ---------------------------------------------------------------------------
// Phase C: attn = sigmoid(h @ attn_w^T + attn_b) broadcast to (64,32,32);
// also emit x_instr_rep = h. h comes packed in hslot slot 0 (tag 1024).
// (All groups store identical bits for tag 1024, so last-writer is benign.)
// ---------------------------------------------------------------------------
__global__ __launch_bounds__(256) void head_kernel(
    const u64* __restrict__ hpacked, const float* __restrict__ attn_w,
    const float* __restrict__ attn_b, float* __restrict__ out)
{
  __shared__ float red[4];
  __shared__ float aval;
  const int r   = blockIdx.x;   // 0..63
  const int tid = threadIdx.x;

  float h0 = __uint_as_float((unsigned)(hpacked[tid]       & 0xffffffffu));
  float h1 = __uint_as_float((unsigned)(hpacked[256 + tid] & 0xffffffffu));

  float p = attn_w[(size_t)r * HID + tid] * h0
          + attn_w[(size_t)r * HID + 256 + tid] * h1;
#pragma unroll
  for (int off = 1; off < 64; off <<= 1) p += __shfl_xor(p, off, 64);
  if ((tid & 63) == 0) red[tid >> 6] = p;
  __syncthreads();
  if (tid == 0) {
    float sum = red[0] + red[1] + red[2] + red[3] + attn_b[r];
    aval = 1.f / (1.f + __expf(-sum));
  }
  __syncthreads();

  float a = aval;
  float4 av = make_float4(a, a, a, a);
  ((float4*)(out + (size_t)r * 1024))[tid] = av;   // 256*16B = 1024 floats

  if (r == 0) {   // x_instr_rep = h (512 floats) at offset 64*32*32
    out[65536 + tid]       = h0;
    out[65536 + 256 + tid] = h1;
  }
}

// ---------------------------------------------------------------------------
extern "C" void kernel_launch(void* const* d_in, const int* in_sizes, int n_in,
                              void* d_out, int out_size, void* d_ws, size_t ws_size,
                              hipStream_t stream) {
  const int*   tok    = (const int*)  d_in[0];
  const float* emb    = (const float*)d_in[1];
  const float* w_ih   = (const float*)d_in[2];
  const float* w_hh   = (const float*)d_in[3];
  const float* b_ih   = (const float*)d_in[4];
  const float* b_hh   = (const float*)d_in[5];
  const float* attn_w = (const float*)d_in[6];
  const float* attn_b = (const float*)d_in[7];
  float* out = (float*)d_out;

  char* ws = (char*)d_ws;
  float* xg    = (float*)ws;                              // 8 MB
  u64*   hslot = (u64*)(ws + (size_t)SEQ * G4 * 4);       // agent buf, 16 KB
  u64*   hfast = hslot + (size_t)NSLOT * HID;             // L2-local bufs, 128 KB

  // ws is poisoned 0xAA before every launch: zero all h slots (tag 0 == h^0=0).
  hipMemsetAsync(hslot, 0,
                 (size_t)(NSLOT * HID + NGRP * NSLOT * HID) * sizeof(u64),
                 stream);

  dim3 gA(G4 / 64, SEQ / 64);   // 32 x 16 tiles
  xgates_kernel<<<gA, 256, 0, stream>>>(tok, emb, w_ih, b_ih, b_hh, xg);
  lstm_scan_kernel<<<NBLK * NGRP, 512, 0, stream>>>(xg, w_hh, hslot, hfast);
  // h^1024 lands in slot (1024 & 3) == 0.
  head_kernel<<<64, 256, 0, stream>>>(hslot, attn_w, attn_b, out);
}